// Round 1
// baseline (759.171 us; speedup 1.0000x reference)
//
#include <hip/hip_runtime.h>
#include <stdint.h>

#define IN_F 4096
#define OUT_F 14336
#define QBLK 64

__device__ __constant__ float NF4_CODE_C[16] = {
    -1.0f, -0.6961928009986877f, -0.5250730514526367f, -0.39491748809814453f,
    -0.28444138169288635f, -0.18477343022823334f, -0.09105003625154495f, 0.0f,
    0.07958029955625534f, 0.16093020141124725f, 0.24611230194568634f,
    0.33791524171829224f, 0.44070982933044434f, 0.5626170039176941f,
    0.8333911895751953f, 1.0f};

typedef __attribute__((ext_vector_type(8))) short short8;   // 8 bf16 (4 VGPRs)
typedef __attribute__((ext_vector_type(4))) float f32x4;    // MFMA acc

__device__ __forceinline__ unsigned short f32_to_bf16_rne(float f) {
    union { float f; uint32_t u; } a; a.f = f;
    uint32_t u = a.u;
    uint32_t r = u + 0x7fffu + ((u >> 16) & 1u);
    return (unsigned short)(r >> 16);
}

// ---------------- Pass 1a: dequant W (int32 idx + per-64 absmax) -> bf16 [N][K]
__global__ void dequant_w_kernel(const int* __restrict__ w,
                                 const float* __restrict__ absmax,
                                 unsigned short* __restrict__ W,
                                 long long n8) {
    long long i = (long long)blockIdx.x * blockDim.x + threadIdx.x;
    long long stride = (long long)gridDim.x * blockDim.x;
    for (; i < n8; i += stride) {
        const int4* p = (const int4*)(w + i * 8);
        int4 v0 = p[0], v1 = p[1];
        float s = absmax[i >> 3];   // 8 elems/thread, 64 elems/block -> block = i/8
        union { unsigned short u[8]; float4 v; } out;
        out.u[0] = f32_to_bf16_rne(NF4_CODE_C[v0.x] * s);
        out.u[1] = f32_to_bf16_rne(NF4_CODE_C[v0.y] * s);
        out.u[2] = f32_to_bf16_rne(NF4_CODE_C[v0.z] * s);
        out.u[3] = f32_to_bf16_rne(NF4_CODE_C[v0.w] * s);
        out.u[4] = f32_to_bf16_rne(NF4_CODE_C[v1.x] * s);
        out.u[5] = f32_to_bf16_rne(NF4_CODE_C[v1.y] * s);
        out.u[6] = f32_to_bf16_rne(NF4_CODE_C[v1.z] * s);
        out.u[7] = f32_to_bf16_rne(NF4_CODE_C[v1.w] * s);
        *(float4*)(W + i * 8) = out.v;
    }
}

// ---------------- Pass 1b: convert x fp32 -> bf16 [M][K]
__global__ void cvt_x_kernel(const float* __restrict__ x,
                             unsigned short* __restrict__ xb,
                             long long n8) {
    long long i = (long long)blockIdx.x * blockDim.x + threadIdx.x;
    long long stride = (long long)gridDim.x * blockDim.x;
    for (; i < n8; i += stride) {
        const float4* p = (const float4*)(x + i * 8);
        float4 a = p[0], b = p[1];
        union { unsigned short u[8]; float4 v; } out;
        out.u[0] = f32_to_bf16_rne(a.x);
        out.u[1] = f32_to_bf16_rne(a.y);
        out.u[2] = f32_to_bf16_rne(a.z);
        out.u[3] = f32_to_bf16_rne(a.w);
        out.u[4] = f32_to_bf16_rne(b.x);
        out.u[5] = f32_to_bf16_rne(b.y);
        out.u[6] = f32_to_bf16_rne(b.z);
        out.u[7] = f32_to_bf16_rne(b.w);
        *(float4*)(xb + i * 8) = out.v;
    }
}

// ---------------- Pass 2: bf16 GEMM, C[m][n] = sum_k A[m][k]*B[n][k] + bias[n]
// m97 structure: 128x128 tile, BK=32, 4 waves (2x2), each wave 64x64 out,
// global_load_lds width-16 staging, 16x16x32 bf16 MFMA.
__device__ __forceinline__ void llds16(const unsigned short* g, unsigned short* l) {
    __builtin_amdgcn_global_load_lds(
        (const __attribute__((address_space(1))) unsigned int*)g,
        (__attribute__((address_space(3))) unsigned int*)l,
        16, 0, 0);
}

__global__ void __launch_bounds__(256)
gemm_bt_bf16(const unsigned short* __restrict__ A,  // [M][K] bf16 bits
             const unsigned short* __restrict__ B,  // [N][K] bf16 bits
             const float* __restrict__ bias,
             float* __restrict__ C, int M, int N, int K) {
    __shared__ unsigned short sA[128 * 32];
    __shared__ unsigned short sB[128 * 32];
    const int tid  = threadIdx.x;
    const int lane = tid & 63;
    const int w    = tid >> 6;        // wave 0..3
    const int wr   = w >> 1;          // wave row (0..1)
    const int wc   = w & 1;           // wave col (0..1)
    const int brow = blockIdx.y * 128;
    const int bcol = blockIdx.x * 128;

    f32x4 acc[4][4] = {};

    // staging: wave w covers tile rows [w*32, w*32+32) via 2 instructions
    const int srow  = w * 32 + (lane >> 2);    // rows for j=0; +16 for j=1
    const int skoff = (lane & 3) * 8;          // k element offset within BK
    const unsigned short* gA = A + (size_t)(brow + srow) * K + skoff;
    const unsigned short* gB = B + (size_t)(bcol + srow) * K + skoff;
    unsigned short* lA = sA + w * 1024;        // wave-uniform LDS base (elems)
    unsigned short* lB = sB + w * 1024;

    const int kq = (lane >> 4) * 8;            // frag k offset
    const int rA = wr * 64 + (lane & 15);      // frag row in A tile
    const int rB = wc * 64 + (lane & 15);      // frag row in B tile

    const int nk = K >> 5;
    for (int t = 0; t < nk; ++t) {
        const size_t k0 = (size_t)t << 5;
        llds16(gA + k0,                  lA);
        llds16(gA + k0 + (size_t)16 * K, lA + 512);
        llds16(gB + k0,                  lB);
        llds16(gB + k0 + (size_t)16 * K, lB + 512);
        __syncthreads();   // drains vmcnt before barrier (compiler-emitted)

        short8 af[4], bfr[4];
        #pragma unroll
        for (int i = 0; i < 4; ++i) {
            af[i]  = *(const short8*)&sA[(rA + i * 16) * 32 + kq];
            bfr[i] = *(const short8*)&sB[(rB + i * 16) * 32 + kq];
        }
        #pragma unroll
        for (int mi = 0; mi < 4; ++mi)
            #pragma unroll
            for (int ni = 0; ni < 4; ++ni)
                acc[mi][ni] = __builtin_amdgcn_mfma_f32_16x16x32_bf16(
                    af[mi], bfr[ni], acc[mi][ni], 0, 0, 0);
        __syncthreads();   // all reads done before next stage overwrites
    }

    // epilogue: D col = lane&15, row = (lane>>4)*4 + j   [guide §3, m89/m91]
    #pragma unroll
    for (int ni = 0; ni < 4; ++ni) {
        const int n = bcol + wc * 64 + ni * 16 + (lane & 15);
        const float bv = bias[n];
        #pragma unroll
        for (int mi = 0; mi < 4; ++mi) {
            #pragma unroll
            for (int j = 0; j < 4; ++j) {
                const int m = brow + wr * 64 + mi * 16 + (lane >> 4) * 4 + j;
                C[(size_t)m * N + n] = acc[mi][ni][j] + bv;
            }
        }
    }
}

// ---------------- fallback: naive fused fp32 (only if ws too small)
__global__ void naive_fused(const float* __restrict__ x, const int* __restrict__ w,
                            const float* __restrict__ am, const float* __restrict__ bias,
                            float* __restrict__ out, int M) {
    long long o = (long long)blockIdx.x * blockDim.x + threadIdx.x;
    if (o >= (long long)M * OUT_F) return;
    int m = (int)(o / OUT_F), n = (int)(o % OUT_F);
    const int* wr_ = w + (size_t)n * IN_F;
    const float* xr = x + (size_t)m * IN_F;
    const float* amr = am + (size_t)n * (IN_F / QBLK);
    float sum = 0.f;
    for (int k = 0; k < IN_F; ++k)
        sum += xr[k] * NF4_CODE_C[wr_[k]] * amr[k >> 6];
    out[o] = sum + bias[n];
}

extern "C" void kernel_launch(void* const* d_in, const int* in_sizes, int n_in,
                              void* d_out, int out_size, void* d_ws, size_t ws_size,
                              hipStream_t stream) {
    const float* x      = (const float*)d_in[0];
    const int*   w_idx  = (const int*)d_in[1];
    const float* absmax = (const float*)d_in[2];
    const float* bias   = (const float*)d_in[3];
    float* out = (float*)d_out;

    const int M = in_sizes[0] / IN_F;   // 4096
    const int N = OUT_F;                // 14336
    const int K = IN_F;                 // 4096

    const size_t needW = (size_t)N * K * 2;       // 117.4 MB bf16 W
    const size_t needX = (size_t)M * K * 2;       // 33.5 MB bf16 x
    if (ws_size >= needW + needX) {
        unsigned short* Wb = (unsigned short*)d_ws;
        unsigned short* Xb = (unsigned short*)((char*)d_ws + needW);

        long long n8w = (long long)N * K / 8;
        dequant_w_kernel<<<8192, 256, 0, stream>>>(w_idx, absmax, Wb, n8w);
        long long n8x = (long long)M * K / 8;
        cvt_x_kernel<<<4096, 256, 0, stream>>>(x, Xb, n8x);

        dim3 grid(N / 128, M / 128);
        gemm_bt_bf16<<<grid, 256, 0, stream>>>(Xb, Wb, bias, out, M, N, K);
    } else {
        long long total = (long long)M * OUT_F;
        int blocks = (int)((total + 255) / 256);
        naive_fused<<<blocks, 256, 0, stream>>>(x, w_idx, absmax, bias, out, M);
    }
}

// Round 2
// 585.583 us; speedup vs baseline: 1.2964x; 1.2964x over previous
//
#include <hip/hip_runtime.h>
#include <stdint.h>

#define IN_F 4096
#define OUT_F 14336
#define QBLK 64

__device__ __constant__ float NF4_CODE_C[16] = {
    -1.0f, -0.6961928009986877f, -0.5250730514526367f, -0.39491748809814453f,
    -0.28444138169288635f, -0.18477343022823334f, -0.09105003625154495f, 0.0f,
    0.07958029955625534f, 0.16093020141124725f, 0.24611230194568634f,
    0.33791524171829224f, 0.44070982933044434f, 0.5626170039176941f,
    0.8333911895751953f, 1.0f};

typedef __attribute__((ext_vector_type(8))) short short8;   // 8 bf16 (4 VGPRs)
typedef __attribute__((ext_vector_type(4))) float f32x4;    // MFMA acc

__device__ __forceinline__ unsigned short f32_to_bf16_rne(float f) {
    union { float f; uint32_t u; } a; a.f = f;
    uint32_t u = a.u;
    uint32_t r = u + 0x7fffu + ((u >> 16) & 1u);
    return (unsigned short)(r >> 16);
}

// ---------------- Pass 1a: dequant W (int32 idx + per-64 absmax) -> bf16 [N][K]
__global__ void dequant_w_kernel(const int* __restrict__ w,
                                 const float* __restrict__ absmax,
                                 unsigned short* __restrict__ W,
                                 long long n8) {
    long long i = (long long)blockIdx.x * blockDim.x + threadIdx.x;
    long long stride = (long long)gridDim.x * blockDim.x;
    for (; i < n8; i += stride) {
        const int4* p = (const int4*)(w + i * 8);
        int4 v0 = p[0], v1 = p[1];
        float s = absmax[i >> 3];
        union { unsigned short u[8]; float4 v; } out;
        out.u[0] = f32_to_bf16_rne(NF4_CODE_C[v0.x] * s);
        out.u[1] = f32_to_bf16_rne(NF4_CODE_C[v0.y] * s);
        out.u[2] = f32_to_bf16_rne(NF4_CODE_C[v0.z] * s);
        out.u[3] = f32_to_bf16_rne(NF4_CODE_C[v0.w] * s);
        out.u[4] = f32_to_bf16_rne(NF4_CODE_C[v1.x] * s);
        out.u[5] = f32_to_bf16_rne(NF4_CODE_C[v1.y] * s);
        out.u[6] = f32_to_bf16_rne(NF4_CODE_C[v1.z] * s);
        out.u[7] = f32_to_bf16_rne(NF4_CODE_C[v1.w] * s);
        *(float4*)(W + i * 8) = out.v;
    }
}

// ---------------- Pass 1b: convert x fp32 -> bf16 [M][K]
__global__ void cvt_x_kernel(const float* __restrict__ x,
                             unsigned short* __restrict__ xb,
                             long long n8) {
    long long i = (long long)blockIdx.x * blockDim.x + threadIdx.x;
    long long stride = (long long)gridDim.x * blockDim.x;
    for (; i < n8; i += stride) {
        const float4* p = (const float4*)(x + i * 8);
        float4 a = p[0], b = p[1];
        union { unsigned short u[8]; float4 v; } out;
        out.u[0] = f32_to_bf16_rne(a.x);
        out.u[1] = f32_to_bf16_rne(a.y);
        out.u[2] = f32_to_bf16_rne(a.z);
        out.u[3] = f32_to_bf16_rne(a.w);
        out.u[4] = f32_to_bf16_rne(b.x);
        out.u[5] = f32_to_bf16_rne(b.y);
        out.u[6] = f32_to_bf16_rne(b.z);
        out.u[7] = f32_to_bf16_rne(b.w);
        *(float4*)(xb + i * 8) = out.v;
    }
}

// ---------------- Pass 2: deep-pipelined bf16 GEMM (B^T), 256x256 tile, BK=32,
// 4 LDS K-tile buffers, counted vmcnt (never 0 in main loop), 1 barrier/K-tile.
__device__ __forceinline__ void llds16(const unsigned short* g, unsigned short* l) {
    __builtin_amdgcn_global_load_lds(
        (const __attribute__((address_space(1))) unsigned int*)g,
        (__attribute__((address_space(3))) unsigned int*)l,
        16, 0, 0);
}

#define GK 4096            // K (hardcoded: stage offsets use it)
#define GN 14336           // N

__global__ void __launch_bounds__(512, 2)
gemm_pipe_bf16(const unsigned short* __restrict__ A,  // [M][4096] bf16 bits
               const unsigned short* __restrict__ B,  // [14336][4096] bf16 bits
               const float* __restrict__ bias,
               float* __restrict__ C, int Mtiles) {
    // 4 buffers x (A 256x32 + B 256x32) bf16 = 4 x 32KB = 128 KiB
    __shared__ unsigned short lds[4 * 16384];
    const int tid  = threadIdx.x;
    const int lane = tid & 63;
    const int wv   = tid >> 6;        // wave 0..7
    const int wr   = wv >> 2;         // M half (0..1)
    const int wc   = wv & 3;          // N quarter (0..3)

    // T1: bijective XCD swizzle (m204), n-major within chunk for B-panel L2 reuse
    const int nwg = gridDim.x;
    const int q = nwg >> 3, r = nwg & 7;
    const int xcd = blockIdx.x & 7, loc = blockIdx.x >> 3;
    const int s = (xcd < r ? xcd * (q + 1) : r * (q + 1) + (xcd - r) * q) + loc;
    const int tm = s % Mtiles;
    const int tn = s / Mtiles;
    const int brow = tm * 256;
    const int bcol = tn * 256;

    f32x4 acc[8][4] = {};

    // staging: thread T -> row T>>2 (of 128), 16B chunk T&3; two row-halves/load
    const int srow   = tid >> 2;
    const int schunk = tid & 3;
    const unsigned short* gA = A + (size_t)(brow + srow) * GK + schunk * 8;
    const unsigned short* gB = B + (size_t)(bcol + srow) * GK + schunk * 8;

    // frag element offsets within a buffer
    const int aoff = (wr * 128 + (lane & 15)) * 32 + (lane >> 4) * 8;
    const int boff = 8192 + (wc * 64 + (lane & 15)) * 32 + (lane >> 4) * 8;

#define STAGE(T, BUF) do {                                            \
        const unsigned short* a0 = gA + (size_t)(T) * 32;             \
        const unsigned short* b0 = gB + (size_t)(T) * 32;             \
        unsigned short* l = &lds[(BUF) * 16384 + wv * 512];           \
        llds16(a0,            l);                                     \
        llds16(a0 + 128 * GK, l + 4096);                              \
        llds16(b0,            l + 8192);                              \
        llds16(b0 + 128 * GK, l + 12288);                             \
    } while (0)

#define COMPUTE(BUF) do {                                             \
        const unsigned short* p = &lds[(BUF) * 16384];                \
        short8 af[8]; short8 bfv[4];                                  \
        _Pragma("unroll")                                             \
        for (int i = 0; i < 8; ++i) af[i]  = *(const short8*)&p[aoff + i * 512]; \
        _Pragma("unroll")                                             \
        for (int n = 0; n < 4; ++n) bfv[n] = *(const short8*)&p[boff + n * 512]; \
        __builtin_amdgcn_s_setprio(1);                                \
        _Pragma("unroll")                                             \
        for (int i = 0; i < 8; ++i)                                   \
            _Pragma("unroll")                                         \
            for (int n = 0; n < 4; ++n)                               \
                acc[i][n] = __builtin_amdgcn_mfma_f32_16x16x32_bf16(  \
                    af[i], bfv[n], acc[i][n], 0, 0, 0);               \
        __builtin_amdgcn_s_setprio(0);                                \
    } while (0)

#define VMW(N) asm volatile("s_waitcnt vmcnt(" #N ")" ::: "memory")
#define BAR()  __builtin_amdgcn_s_barrier()

    // prologue: 3 tiles in flight
    STAGE(0, 0); STAGE(1, 1); STAGE(2, 2);

    // main loop: tiles 0..123 (nk = 4096/32 = 128)
    for (int tt = 0; tt < 124; tt += 4) {
        VMW(8); BAR(); STAGE(tt + 3, 3); COMPUTE(0);
        VMW(8); BAR(); STAGE(tt + 4, 0); COMPUTE(1);
        VMW(8); BAR(); STAGE(tt + 5, 1); COMPUTE(2);
        VMW(8); BAR(); STAGE(tt + 6, 2); COMPUTE(3);
    }
    // peeled tail: t = 124..127, drain 8 -> 8 -> 4 -> 0
    VMW(8); BAR(); STAGE(127, 3); COMPUTE(0);
    VMW(8); BAR(); COMPUTE(1);
    VMW(4); BAR(); COMPUTE(2);
    VMW(0); BAR(); COMPUTE(3);

#undef STAGE
#undef COMPUTE
#undef VMW
#undef BAR

    // epilogue: D col = lane&15, row = (lane>>4)*4 + j
    #pragma unroll
    for (int n = 0; n < 4; ++n) {
        const int col = bcol + wc * 64 + n * 16 + (lane & 15);
        const float bv = bias[col];
        #pragma unroll
        for (int i = 0; i < 8; ++i) {
            #pragma unroll
            for (int j = 0; j < 4; ++j) {
                const int row = brow + wr * 128 + i * 16 + (lane >> 4) * 4 + j;
                C[(size_t)row * GN + col] = acc[i][n][j] + bv;
            }
        }
    }
}

// ---------------- fallback: naive fused fp32 (only if ws too small)
__global__ void naive_fused(const float* __restrict__ x, const int* __restrict__ w,
                            const float* __restrict__ am, const float* __restrict__ bias,
                            float* __restrict__ out, int M) {
    long long o = (long long)blockIdx.x * blockDim.x + threadIdx.x;
    if (o >= (long long)M * OUT_F) return;
    int m = (int)(o / OUT_F), n = (int)(o % OUT_F);
    const int* wr_ = w + (size_t)n * IN_F;
    const float* xr = x + (size_t)m * IN_F;
    const float* amr = am + (size_t)n * (IN_F / QBLK);
    float sum = 0.f;
    for (int k = 0; k < IN_F; ++k)
        sum += xr[k] * NF4_CODE_C[wr_[k]] * amr[k >> 6];
    out[o] = sum + bias[n];
}

extern "C" void kernel_launch(void* const* d_in, const int* in_sizes, int n_in,
                              void* d_out, int out_size, void* d_ws, size_t ws_size,
                              hipStream_t stream) {
    const float* x      = (const float*)d_in[0];
    const int*   w_idx  = (const int*)d_in[1];
    const float* absmax = (const float*)d_in[2];
    const float* bias   = (const float*)d_in[3];
    float* out = (float*)d_out;

    const int M = in_sizes[0] / IN_F;   // 4096
    const int N = OUT_F;                // 14336
    const int K = IN_F;                 // 4096

    const size_t needW = (size_t)N * K * 2;
    const size_t needX = (size_t)M * K * 2;
    if (ws_size >= needW + needX && (M % 256) == 0) {
        unsigned short* Wb = (unsigned short*)d_ws;
        unsigned short* Xb = (unsigned short*)((char*)d_ws + needW);

        long long n8w = (long long)N * K / 8;
        dequant_w_kernel<<<8192, 256, 0, stream>>>(w_idx, absmax, Wb, n8w);
        long long n8x = (long long)M * K / 8;
        cvt_x_kernel<<<4096, 256, 0, stream>>>(x, Xb, n8x);

        const int Mtiles = M / 256;
        dim3 grid(Mtiles * (N / 256));
        gemm_pipe_bf16<<<grid, 512, 0, stream>>>(Xb, Wb, bias, out, Mtiles);
    } else {
        long long total = (long long)M * OUT_F;
        int blocks = (int)((total + 255) / 256);
        naive_fused<<<blocks, 256, 0, stream>>>(x, w_idx, absmax, bias, out, M);
    }
}

// Round 3
// 568.131 us; speedup vs baseline: 1.3363x; 1.0307x over previous
//
#include <hip/hip_runtime.h>
#include <stdint.h>

#define IN_F 4096
#define OUT_F 14336
#define QBLK 64

__device__ __constant__ float NF4_CODE_C[16] = {
    -1.0f, -0.6961928009986877f, -0.5250730514526367f, -0.39491748809814453f,
    -0.28444138169288635f, -0.18477343022823334f, -0.09105003625154495f, 0.0f,
    0.07958029955625534f, 0.16093020141124725f, 0.24611230194568634f,
    0.33791524171829224f, 0.44070982933044434f, 0.5626170039176941f,
    0.8333911895751953f, 1.0f};

typedef __attribute__((ext_vector_type(8))) short short8;   // 8 bf16 (4 VGPRs)
typedef __attribute__((ext_vector_type(4))) float f32x4;    // MFMA acc

__device__ __forceinline__ unsigned short f32_to_bf16_rne(float f) {
    union { float f; uint32_t u; } a; a.f = f;
    uint32_t u = a.u;
    uint32_t r = u + 0x7fffu + ((u >> 16) & 1u);
    return (unsigned short)(r >> 16);
}

// ---------------- Pass 1a: dequant W (int32 idx + per-64 absmax) -> bf16 [N][K]
__global__ void dequant_w_kernel(const int* __restrict__ w,
                                 const float* __restrict__ absmax,
                                 unsigned short* __restrict__ W,
                                 long long n8) {
    long long i = (long long)blockIdx.x * blockDim.x + threadIdx.x;
    long long stride = (long long)gridDim.x * blockDim.x;
    for (; i < n8; i += stride) {
        const int4* p = (const int4*)(w + i * 8);
        int4 v0 = p[0], v1 = p[1];
        float s = absmax[i >> 3];
        union { unsigned short u[8]; float4 v; } out;
        out.u[0] = f32_to_bf16_rne(NF4_CODE_C[v0.x] * s);
        out.u[1] = f32_to_bf16_rne(NF4_CODE_C[v0.y] * s);
        out.u[2] = f32_to_bf16_rne(NF4_CODE_C[v0.z] * s);
        out.u[3] = f32_to_bf16_rne(NF4_CODE_C[v0.w] * s);
        out.u[4] = f32_to_bf16_rne(NF4_CODE_C[v1.x] * s);
        out.u[5] = f32_to_bf16_rne(NF4_CODE_C[v1.y] * s);
        out.u[6] = f32_to_bf16_rne(NF4_CODE_C[v1.z] * s);
        out.u[7] = f32_to_bf16_rne(NF4_CODE_C[v1.w] * s);
        *(float4*)(W + i * 8) = out.v;
    }
}

// ---------------- Pass 1b: convert x fp32 -> bf16 [M][K]
__global__ void cvt_x_kernel(const float* __restrict__ x,
                             unsigned short* __restrict__ xb,
                             long long n8) {
    long long i = (long long)blockIdx.x * blockDim.x + threadIdx.x;
    long long stride = (long long)gridDim.x * blockDim.x;
    for (; i < n8; i += stride) {
        const float4* p = (const float4*)(x + i * 8);
        float4 a = p[0], b = p[1];
        union { unsigned short u[8]; float4 v; } out;
        out.u[0] = f32_to_bf16_rne(a.x);
        out.u[1] = f32_to_bf16_rne(a.y);
        out.u[2] = f32_to_bf16_rne(a.z);
        out.u[3] = f32_to_bf16_rne(a.w);
        out.u[4] = f32_to_bf16_rne(b.x);
        out.u[5] = f32_to_bf16_rne(b.y);
        out.u[6] = f32_to_bf16_rne(b.z);
        out.u[7] = f32_to_bf16_rne(b.w);
        *(float4*)(xb + i * 8) = out.v;
    }
}

// ---------------- Pass 2: deep-pipelined bf16 GEMM (B^T), 256x256 tile, BK=32,
// 4 LDS K-tile buffers, counted vmcnt (never 0 in main loop), 1 barrier/K-tile,
// T2 XOR-swizzle: LDS[r][s] holds global chunk s ^ g(r), g(r)=(r>>1)&3.
// Write side: linear LDS dest (global_load_lds), pre-swizzled global chunk.
// Read side: kq = ((lane>>4) ^ g(row))*8. Lanes 0-7 cover all 32 banks.
__device__ __forceinline__ void llds16(const unsigned short* g, unsigned short* l) {
    __builtin_amdgcn_global_load_lds(
        (const __attribute__((address_space(1))) unsigned int*)g,
        (__attribute__((address_space(3))) unsigned int*)l,
        16, 0, 0);
}

#define GK 4096            // K (hardcoded: stage offsets use it)
#define GN 14336           // N

__global__ void __launch_bounds__(512, 2)
gemm_pipe_bf16(const unsigned short* __restrict__ A,  // [M][4096] bf16 bits
               const unsigned short* __restrict__ B,  // [14336][4096] bf16 bits
               const float* __restrict__ bias,
               float* __restrict__ C, int Mtiles) {
    // 4 buffers x (A 256x32 + B 256x32) bf16 = 4 x 32KB = 128 KiB
    __shared__ unsigned short lds[4 * 16384];
    const int tid  = threadIdx.x;
    const int lane = tid & 63;
    const int wv   = tid >> 6;        // wave 0..7
    const int wr   = wv >> 2;         // M half (0..1)
    const int wc   = wv & 3;          // N quarter (0..3)

    // T1: bijective XCD swizzle (m204), m-major within chunk
    const int nwg = gridDim.x;
    const int q = nwg >> 3, r = nwg & 7;
    const int xcd = blockIdx.x & 7, loc = blockIdx.x >> 3;
    const int s = (xcd < r ? xcd * (q + 1) : r * (q + 1) + (xcd - r) * q) + loc;
    const int tm = s % Mtiles;
    const int tn = s / Mtiles;
    const int brow = tm * 256;
    const int bcol = tn * 256;

    f32x4 acc[8][4] = {};

    // staging: thread T -> row T>>2 (of 128), LDS slot T&3 (linear dest),
    // global 16B-chunk (T&3) ^ g(row) where g(row) = (row>>1)&3 = (T>>3)&3
    const int srow   = tid >> 2;
    const int gchunk = (tid & 3) ^ ((tid >> 3) & 3);
    const unsigned short* gA = A + (size_t)(brow + srow) * GK + gchunk * 8;
    const unsigned short* gB = B + (size_t)(bcol + srow) * GK + gchunk * 8;

    // frag element offsets within a buffer; read slot = (lane>>4) ^ g(row),
    // g(row) = ((lane&15)>>1)&3  (row = base + (lane&15) + 16*i, bases ≡ 0 mod 8)
    const int kqs  = (((lane >> 4) ^ (((lane & 15) >> 1) & 3))) * 8;
    const int aoff = (wr * 128 + (lane & 15)) * 32 + kqs;
    const int boff = 8192 + (wc * 64 + (lane & 15)) * 32 + kqs;

#define STAGE(T, BUF) do {                                            \
        const unsigned short* a0 = gA + (size_t)(T) * 32;             \
        const unsigned short* b0 = gB + (size_t)(T) * 32;             \
        unsigned short* l = &lds[(BUF) * 16384 + wv * 512];           \
        llds16(a0,            l);                                     \
        llds16(a0 + 128 * GK, l + 4096);                              \
        llds16(b0,            l + 8192);                              \
        llds16(b0 + 128 * GK, l + 12288);                             \
    } while (0)

#define COMPUTE(BUF) do {                                             \
        const unsigned short* p = &lds[(BUF) * 16384];                \
        short8 af[8]; short8 bfv[4];                                  \
        _Pragma("unroll")                                             \
        for (int i = 0; i < 8; ++i) af[i]  = *(const short8*)&p[aoff + i * 512]; \
        _Pragma("unroll")                                             \
        for (int n = 0; n < 4; ++n) bfv[n] = *(const short8*)&p[boff + n * 512]; \
        __builtin_amdgcn_s_setprio(1);                                \
        _Pragma("unroll")                                             \
        for (int i = 0; i < 8; ++i)                                   \
            _Pragma("unroll")                                         \
            for (int n = 0; n < 4; ++n)                               \
                acc[i][n] = __builtin_amdgcn_mfma_f32_16x16x32_bf16(  \
                    af[i], bfv[n], acc[i][n], 0, 0, 0);               \
        __builtin_amdgcn_s_setprio(0);                                \
    } while (0)

#define VMW(N) asm volatile("s_waitcnt vmcnt(" #N ")" ::: "memory")
#define BAR()  __builtin_amdgcn_s_barrier()

    // prologue: 3 tiles in flight
    STAGE(0, 0); STAGE(1, 1); STAGE(2, 2);

    // main loop: tiles 0..123 (nk = 4096/32 = 128)
    for (int tt = 0; tt < 124; tt += 4) {
        VMW(8); BAR(); STAGE(tt + 3, 3); COMPUTE(0);
        VMW(8); BAR(); STAGE(tt + 4, 0); COMPUTE(1);
        VMW(8); BAR(); STAGE(tt + 5, 1); COMPUTE(2);
        VMW(8); BAR(); STAGE(tt + 6, 2); COMPUTE(3);
    }
    // peeled tail: t = 124..127, drain 8 -> 8 -> 4 -> 0
    VMW(8); BAR(); STAGE(127, 3); COMPUTE(0);
    VMW(8); BAR(); COMPUTE(1);
    VMW(4); BAR(); COMPUTE(2);
    VMW(0); BAR(); COMPUTE(3);

#undef STAGE
#undef COMPUTE
#undef VMW
#undef BAR

    // epilogue: D col = lane&15, row = (lane>>4)*4 + j
    #pragma unroll
    for (int n = 0; n < 4; ++n) {
        const int col = bcol + wc * 64 + n * 16 + (lane & 15);
        const float bv = bias[col];
        #pragma unroll
        for (int i = 0; i < 8; ++i) {
            #pragma unroll
            for (int j = 0; j < 4; ++j) {
                const int row = brow + wr * 128 + i * 16 + (lane >> 4) * 4 + j;
                C[(size_t)row * GN + col] = acc[i][n][j] + bv;
            }
        }
    }
}

// ---------------- fallback: naive fused fp32 (only if ws too small)
__global__ void naive_fused(const float* __restrict__ x, const int* __restrict__ w,
                            const float* __restrict__ am, const float* __restrict__ bias,
                            float* __restrict__ out, int M) {
    long long o = (long long)blockIdx.x * blockDim.x + threadIdx.x;
    if (o >= (long long)M * OUT_F) return;
    int m = (int)(o / OUT_F), n = (int)(o % OUT_F);
    const int* wr_ = w + (size_t)n * IN_F;
    const float* xr = x + (size_t)m * IN_F;
    const float* amr = am + (size_t)n * (IN_F / QBLK);
    float sum = 0.f;
    for (int k = 0; k < IN_F; ++k)
        sum += xr[k] * NF4_CODE_C[wr_[k]] * amr[k >> 6];
    out[o] = sum + bias[n];
}

extern "C" void kernel_launch(void* const* d_in, const int* in_sizes, int n_in,
                              void* d_out, int out_size, void* d_ws, size_t ws_size,
                              hipStream_t stream) {
    const float* x      = (const float*)d_in[0];
    const int*   w_idx  = (const int*)d_in[1];
    const float* absmax = (const float*)d_in[2];
    const float* bias   = (const float*)d_in[3];
    float* out = (float*)d_out;

    const int M = in_sizes[0] / IN_F;   // 4096
    const int N = OUT_F;                // 14336
    const int K = IN_F;                 // 4096

    const size_t needW = (size_t)N * K * 2;
    const size_t needX = (size_t)M * K * 2;
    if (ws_size >= needW + needX && (M % 256) == 0) {
        unsigned short* Wb = (unsigned short*)d_ws;
        unsigned short* Xb = (unsigned short*)((char*)d_ws + needW);

        long long n8w = (long long)N * K / 8;
        dequant_w_kernel<<<8192, 256, 0, stream>>>(w_idx, absmax, Wb, n8w);
        long long n8x = (long long)M * K / 8;
        cvt_x_kernel<<<4096, 256, 0, stream>>>(x, Xb, n8x);

        const int Mtiles = M / 256;
        dim3 grid(Mtiles * (N / 256));
        gemm_pipe_bf16<<<grid, 512, 0, stream>>>(Xb, Wb, bias, out, Mtiles);
    } else {
        long long total = (long long)M * OUT_F;
        int blocks = (int)((total + 255) / 256);
        naive_fused<<<blocks, 256, 0, stream>>>(x, w_idx, absmax, bias, out, M);
    }
}

// Round 4
// 518.882 us; speedup vs baseline: 1.4631x; 1.0949x over previous
//
#include <hip/hip_runtime.h>
#include <stdint.h>

#define IN_F 4096
#define OUT_F 14336
#define QBLK 64

__device__ __constant__ float NF4_CODE_C[16] = {
    -1.0f, -0.6961928009986877f, -0.5250730514526367f, -0.39491748809814453f,
    -0.28444138169288635f, -0.18477343022823334f, -0.09105003625154495f, 0.0f,
    0.07958029955625534f, 0.16093020141124725f, 0.24611230194568634f,
    0.33791524171829224f, 0.44070982933044434f, 0.5626170039176941f,
    0.8333911895751953f, 1.0f};

typedef __attribute__((ext_vector_type(8))) short short8;   // 8 bf16 (4 VGPRs)
typedef __attribute__((ext_vector_type(4))) float f32x4;    // MFMA acc

__device__ __forceinline__ unsigned short f32_to_bf16_rne(float f) {
    union { float f; uint32_t u; } a; a.f = f;
    uint32_t u = a.u;
    uint32_t r = u + 0x7fffu + ((u >> 16) & 1u);
    return (unsigned short)(r >> 16);
}

// ---------------- Pass 1a: dequant W -> bf16 [N][K]
__global__ void dequant_w_kernel(const int* __restrict__ w,
                                 const float* __restrict__ absmax,
                                 unsigned short* __restrict__ W,
                                 long long n8) {
    long long i = (long long)blockIdx.x * blockDim.x + threadIdx.x;
    long long stride = (long long)gridDim.x * blockDim.x;
    for (; i < n8; i += stride) {
        const int4* p = (const int4*)(w + i * 8);
        int4 v0 = p[0], v1 = p[1];
        float s = absmax[i >> 3];
        union { unsigned short u[8]; float4 v; } out;
        out.u[0] = f32_to_bf16_rne(NF4_CODE_C[v0.x] * s);
        out.u[1] = f32_to_bf16_rne(NF4_CODE_C[v0.y] * s);
        out.u[2] = f32_to_bf16_rne(NF4_CODE_C[v0.z] * s);
        out.u[3] = f32_to_bf16_rne(NF4_CODE_C[v0.w] * s);
        out.u[4] = f32_to_bf16_rne(NF4_CODE_C[v1.x] * s);
        out.u[5] = f32_to_bf16_rne(NF4_CODE_C[v1.y] * s);
        out.u[6] = f32_to_bf16_rne(NF4_CODE_C[v1.z] * s);
        out.u[7] = f32_to_bf16_rne(NF4_CODE_C[v1.w] * s);
        *(float4*)(W + i * 8) = out.v;
    }
}

// ---------------- Pass 1b: x fp32 -> bf16
__global__ void cvt_x_kernel(const float* __restrict__ x,
                             unsigned short* __restrict__ xb,
                             long long n8) {
    long long i = (long long)blockIdx.x * blockDim.x + threadIdx.x;
    long long stride = (long long)gridDim.x * blockDim.x;
    for (; i < n8; i += stride) {
        const float4* p = (const float4*)(x + i * 8);
        float4 a = p[0], b = p[1];
        union { unsigned short u[8]; float4 v; } out;
        out.u[0] = f32_to_bf16_rne(a.x);
        out.u[1] = f32_to_bf16_rne(a.y);
        out.u[2] = f32_to_bf16_rne(a.z);
        out.u[3] = f32_to_bf16_rne(a.w);
        out.u[4] = f32_to_bf16_rne(b.x);
        out.u[5] = f32_to_bf16_rne(b.y);
        out.u[6] = f32_to_bf16_rne(b.z);
        out.u[7] = f32_to_bf16_rne(b.w);
        *(float4*)(xb + i * 8) = out.v;
    }
}

// ---------------- Pass 2: 8-phase-style pipelined bf16 GEMM (B^T)
// 256x256 tile, BK=64, 2 LDS buffers (128 KiB), 8 waves (2M x 4N),
// wave tile 128x64. Per K-tile: 4 phases, each = {stage 2 chunk-loads of
// tile t+1 (opposite buffer) -> ds_read quadrant -> 16 MFMA -> vmcnt(4)
// -> barrier}. Stage/read ledger gives every chunk >=3-phase landing lag.
__device__ __forceinline__ void llds16(const unsigned short* g, unsigned short* l) {
    __builtin_amdgcn_global_load_lds(
        (const __attribute__((address_space(1))) unsigned int*)g,
        (__attribute__((address_space(3))) unsigned int*)l,
        16, 0, 0);
}

#define GK 4096
#define GN 14336

__global__ void __launch_bounds__(512, 2)
gemm_8ph_bf16(const unsigned short* __restrict__ A,  // [M][4096] bf16 bits
              const unsigned short* __restrict__ B,  // [14336][4096] bf16 bits
              const float* __restrict__ bias,
              float* __restrict__ C, int Mtiles) {
    // 2 buffers x (A 256x64 + B 256x64) bf16 = 2 x 64KB = 128 KiB
    __shared__ unsigned short lds[65536];
    const int tid  = threadIdx.x;
    const int lane = tid & 63;
    const int wv   = tid >> 6;        // wave 0..7
    const int wr   = wv >> 2;         // M half
    const int wc   = wv & 3;          // N quarter

    // T1: bijective XCD swizzle (m204)
    const int nwg = gridDim.x;
    const int q = nwg >> 3, r = nwg & 7;
    const int xcd = blockIdx.x & 7, loc = blockIdx.x >> 3;
    const int s = (xcd < r ? xcd * (q + 1) : r * (q + 1) + (xcd - r) * q) + loc;
    const int tm = s % Mtiles;
    const int tn = s / Mtiles;
    const int brow = tm * 256;
    const int bcol = tn * 256;

    f32x4 acc[8][4] = {};

    // ---- staging addresses. 1 load-instr = 64 rows x 64 cols (8 KB).
    // lane l: row += l>>3, slot (l&7) linear in LDS; global 16B-chunk
    // pre-swizzled: gch = (l&7) ^ ((l>>3)&7)  [T2, rule #21 both-sides]
    const int l8 = lane >> 3, l7 = lane & 7;
    const int gch = (l7 ^ (l8 & 7)) * 8;
    const unsigned short* pA = A + (size_t)(brow + wv * 8 + l8) * GK + gch;
    const unsigned short* pB = B + (size_t)(bcol + (wv >> 2) * 64 + (wv & 3) * 8 + l8) * GK + gch;
    const int ldsA = wv * 512;                               // + c*4096 + bO
    const int ldsB = 16384 + (wv >> 2) * 4096 + (wv & 3) * 512; // + P*8192 + q*2048 + bO

    // ---- read offsets (elems). row*64 + slot*8, slot = (kgrp+4*kk)^(row&7)
    const int sl0 = (((lane >> 4)    ) ^ l7) * 8;
    const int sl1 = (((lane >> 4) + 4) ^ l7) * 8;
    const int ab = (wr * 128 + (lane & 15)) * 64;            // + qm*4096 + rt*1024
    const int bb = 16384 + (wc * 64 + (lane & 15)) * 64;     // + qn*2048 + nt*1024

#define ST_A(c, T, O)    llds16(pA + (size_t)(c) * 64 * GK + (size_t)(T) * 64, &lds[(O) + (c) * 4096 + ldsA])
#define ST_B(P, qq, T, O) llds16(pB + (size_t)((P) * 128 + (qq) * 32) * GK + (size_t)(T) * 64, &lds[(O) + (P) * 8192 + (qq) * 2048 + ldsB])

#define RD_A(af, qm, O) do { _Pragma("unroll")                                  \
    for (int rt = 0; rt < 4; ++rt) {                                            \
        af[rt][0] = *(const short8*)&lds[(O) + ab + (qm) * 4096 + rt * 1024 + sl0]; \
        af[rt][1] = *(const short8*)&lds[(O) + ab + (qm) * 4096 + rt * 1024 + sl1]; \
    } } while (0)
#define RD_B(bq, qn, O) do { _Pragma("unroll")                                  \
    for (int nt = 0; nt < 2; ++nt) {                                            \
        bq[nt][0] = *(const short8*)&lds[(O) + bb + (qn) * 2048 + nt * 1024 + sl0]; \
        bq[nt][1] = *(const short8*)&lds[(O) + bb + (qn) * 2048 + nt * 1024 + sl1]; \
    } } while (0)
#define MM(af, bq, i0, n0) do {                                                 \
    __builtin_amdgcn_s_setprio(1);                                              \
    _Pragma("unroll") for (int rt = 0; rt < 4; ++rt)                            \
    _Pragma("unroll") for (int nt = 0; nt < 2; ++nt)                            \
    _Pragma("unroll") for (int kk = 0; kk < 2; ++kk)                            \
        acc[(i0) + rt][(n0) + nt] = __builtin_amdgcn_mfma_f32_16x16x32_bf16(    \
            af[rt][kk], bq[nt][kk], acc[(i0) + rt][(n0) + nt], 0, 0, 0);        \
    __builtin_amdgcn_s_setprio(0);                                              \
} while (0)

#define VMW(N) asm volatile("s_waitcnt vmcnt(" #N ")" ::: "memory")
#define BAR()  __builtin_amdgcn_s_barrier()

// One K-tile: compute buffer O, stage tile T into buffer NO.
// Stage order {A0,A2},{bl0,bl2},{bl1,bl3},{A1,A3}; read order matches
// deadlines: ph1 needs A-qm0+B-qn0 (staged >=2 tiles... >=2 phases before
// prior boundary vmcnt), ph2 needs B-qn1 (lag3), ph3 needs A-qm1 (lag3).
#define TILE_BODY(O, NO, T) do {                                                \
    short8 af0[4][2], af1[4][2], bq0[2][2], bq1[2][2];                          \
    /* ph1: (qm0,qn0) */                                                        \
    ST_A(0, T, NO); ST_A(2, T, NO);                                             \
    RD_A(af0, 0, O); RD_B(bq0, 0, O);                                           \
    MM(af0, bq0, 0, 0);                                                         \
    VMW(4); BAR();                                                              \
    /* ph2: (qm0,qn1) */                                                        \
    ST_B(0, 0, T, NO); ST_B(1, 0, T, NO);                                       \
    RD_B(bq1, 1, O);                                                            \
    MM(af0, bq1, 0, 2);                                                         \
    VMW(4); BAR();                                                              \
    /* ph3: (qm1,qn0) */                                                        \
    ST_B(0, 1, T, NO); ST_B(1, 1, T, NO);                                       \
    RD_A(af1, 1, O);                                                            \
    MM(af1, bq0, 4, 0);                                                         \
    VMW(4); BAR();                                                              \
    /* ph4: (qm1,qn1) */                                                        \
    ST_A(1, T, NO); ST_A(3, T, NO);                                             \
    MM(af1, bq1, 4, 2);                                                         \
    VMW(4); BAR();                                                              \
} while (0)

    // prologue: stage tile 0 into buf0 in deadline order; land first 4 chunks
    ST_A(0, 0, 0); ST_A(2, 0, 0);
    ST_B(0, 0, 0, 0); ST_B(1, 0, 0, 0);
    ST_B(0, 1, 0, 0); ST_B(1, 1, 0, 0);
    ST_A(1, 0, 0); ST_A(3, 0, 0);
    VMW(4); BAR();

    // main: NT=64 K-tiles; tiles 0..62 stage their successor
    for (int t = 0; t < 62; t += 2) {
        TILE_BODY(0,     32768, t + 1);
        TILE_BODY(32768, 0,     t + 2);
    }
    TILE_BODY(0, 32768, 63);   // tile 62, stages tile 63

    { // tail: tile 63 (buf1), no stages, drain 4 -> 2 -> 0
        short8 af0[4][2], af1[4][2], bq0[2][2], bq1[2][2];
        RD_A(af0, 0, 32768); RD_B(bq0, 0, 32768);
        MM(af0, bq0, 0, 0);
        VMW(2); BAR();
        RD_B(bq1, 1, 32768);
        MM(af0, bq1, 0, 2);
        VMW(0); BAR();
        RD_A(af1, 1, 32768);
        MM(af1, bq0, 4, 0);
        MM(af1, bq1, 4, 2);
    }

#undef TILE_BODY
#undef VMW
#undef BAR
#undef MM
#undef RD_A
#undef RD_B
#undef ST_A
#undef ST_B

    // epilogue: D col = lane&15, row = (lane>>4)*4 + j
    #pragma unroll
    for (int n = 0; n < 4; ++n) {
        const int col = bcol + wc * 64 + n * 16 + (lane & 15);
        const float bv = bias[col];
        #pragma unroll
        for (int i = 0; i < 8; ++i) {
            #pragma unroll
            for (int j = 0; j < 4; ++j) {
                const int row = brow + wr * 128 + i * 16 + (lane >> 4) * 4 + j;
                C[(size_t)row * GN + col] = acc[i][n][j] + bv;
            }
        }
    }
}

// ---------------- fallback: naive fused fp32
__global__ void naive_fused(const float* __restrict__ x, const int* __restrict__ w,
                            const float* __restrict__ am, const float* __restrict__ bias,
                            float* __restrict__ out, int M) {
    long long o = (long long)blockIdx.x * blockDim.x + threadIdx.x;
    if (o >= (long long)M * OUT_F) return;
    int m = (int)(o / OUT_F), n = (int)(o % OUT_F);
    const int* wr_ = w + (size_t)n * IN_F;
    const float* xr = x + (size_t)m * IN_F;
    const float* amr = am + (size_t)n * (IN_F / QBLK);
    float sum = 0.f;
    for (int k = 0; k < IN_F; ++k)
        sum += xr[k] * NF4_CODE_C[wr_[k]] * amr[k >> 6];
    out[o] = sum + bias[n];
}

extern "C" void kernel_launch(void* const* d_in, const int* in_sizes, int n_in,
                              void* d_out, int out_size, void* d_ws, size_t ws_size,
                              hipStream_t stream) {
    const float* x      = (const float*)d_in[0];
    const int*   w_idx  = (const int*)d_in[1];
    const float* absmax = (const float*)d_in[2];
    const float* bias   = (const float*)d_in[3];
    float* out = (float*)d_out;

    const int M = in_sizes[0] / IN_F;   // 4096
    const int N = OUT_F;                // 14336
    const int K = IN_F;                 // 4096

    const size_t needW = (size_t)N * K * 2;
    const size_t needX = (size_t)M * K * 2;
    if (ws_size >= needW + needX && (M % 256) == 0) {
        unsigned short* Wb = (unsigned short*)d_ws;
        unsigned short* Xb = (unsigned short*)((char*)d_ws + needW);

        long long n8w = (long long)N * K / 8;
        dequant_w_kernel<<<8192, 256, 0, stream>>>(w_idx, absmax, Wb, n8w);
        long long n8x = (long long)M * K / 8;
        cvt_x_kernel<<<4096, 256, 0, stream>>>(x, Xb, n8x);

        const int Mtiles = M / 256;
        dim3 grid(Mtiles * (N / 256));
        gemm_8ph_bf16<<<grid, 512, 0, stream>>>(Xb, Wb, bias, out, Mtiles);
    } else {
        long long total = (long long)M * OUT_F;
        int blocks = (int)((total + 255) / 256);
        naive_fused<<<blocks, 256, 0, stream>>>(x, w_idx, absmax, bias, out, M);
    }
}